// Round 1
// baseline (409.784 us; speedup 1.0000x reference)
//
#include <hip/hip_runtime.h>
#include <math.h>

// Problem constants (fixed shapes from reference)
#define NB   16384      // memory bank rows
#define DD   2048       // feature dim
#define BQ   64         // batch queries
#define TEMP 0.07f

// ws layout (in floats):
//   fT   [2048*64]  at 0            (f transposed, [d][b])
//   blab [64 ints]  at 131072
//   Wm   [64*256]   at 131136       (per-(query,block) neg running max, y-domain)
//   Ws   [64*256]   at 147520       (sumexp relative to Wm)
//   Wp   [64*256]   at 163904       (pos min, y-domain)

__device__ __forceinline__ void wg_barrier() {
    // barrier that drains LDS ops only (NOT vmcnt) so prefetch loads stay in flight
    asm volatile("s_waitcnt lgkmcnt(0)\ns_barrier" ::: "memory");
}

__device__ __forceinline__ void f4_to_arr(float4 t, float* a) {
    a[0] = t.x; a[1] = t.y; a[2] = t.z; a[3] = t.w;
}

// K0: transpose f [64][2048] -> fT [2048][64]; gather batch labels
__global__ __launch_bounds__(256) void k_prep(const float* __restrict__ f,
                                              const int* __restrict__ indexes,
                                              const int* __restrict__ labels,
                                              float* __restrict__ fT,
                                              int* __restrict__ blab) {
    __shared__ float t[64][65];
    const int tid = threadIdx.x;
    const int d0 = blockIdx.x * 64;
#pragma unroll
    for (int p = 0; p < 16; ++p) {
        int idx = tid + 256 * p;
        int r = idx >> 6, c = idx & 63;
        t[r][c] = f[r * DD + d0 + c];
    }
    __syncthreads();
#pragma unroll
    for (int p = 0; p < 16; ++p) {
        int idx = tid + 256 * p;
        int c2 = idx >> 6, r2 = idx & 63;
        fT[(d0 + c2) * 64 + r2] = t[r2][c2];
    }
    if (blockIdx.x == 0 && tid < 64) blab[tid] = labels[indexes[tid]];
}

// K1: fused  (a) mat tile [64 rows x 64 queries] fp32 GEMM
//            (b) features -> d_out+1 passthrough copy
//            (c) masked online (negmax, sumexp, posmin) partials per block
__global__ __launch_bounds__(256) void k_main(const float* __restrict__ feat,
                                              const float* __restrict__ fT,
                                              const int* __restrict__ labels,
                                              const int* __restrict__ blab,
                                              float* __restrict__ out,
                                              float* __restrict__ Wm,
                                              float* __restrict__ Ws,
                                              float* __restrict__ Wp) {
    __shared__ float Xs[64][68];   // [row][d] pad 68 -> conflict-free b128 reads
    __shared__ float Fs[64][64];   // [d][query]
    __shared__ int   lab_s[64];
    __shared__ int   blab_s[64];
    __shared__ float red_m[16][64];
    __shared__ float red_s[16][64];
    __shared__ float red_p[16][64];

    const int tid = threadIdx.x;
    const int n0  = blockIdx.x * 64;
    if (tid < 64) { lab_s[tid] = labels[n0 + tid]; blab_s[tid] = blab[tid]; }

    const int tx = tid & 15;   // query group: q0..q0+3
    const int ty = tid >> 4;   // row group:   r0..r0+3
    const int q0 = tx * 4;
    const int r0 = ty * 4;

    float acc[4][4];           // [ri][qi]
#pragma unroll
    for (int i = 0; i < 4; ++i)
#pragma unroll
        for (int j = 0; j < 4; ++j) acc[i][j] = 0.f;

    // staging registers, double-buffered
    float4 xa[4], fa[4], xb[4], fb[4];

    // mapping for pass p: vec index v = tid + 256p; r = v>>4; dd = (v&15)*4
#define STAGE_LOAD(d0v, xr, fr)                                                        \
    {                                                                                   \
        _Pragma("unroll")                                                               \
        for (int p = 0; p < 4; ++p) {                                                   \
            int v = tid + 256 * p;                                                      \
            int r = v >> 4, dd = (v & 15) << 2;                                         \
            xr[p] = *(const float4*)&feat[(long long)(n0 + r) * DD + (d0v) + dd];       \
            fr[p] = *(const float4*)&fT[(d0v) * 64 + v * 4];                            \
        }                                                                               \
    }

    STAGE_LOAD(0, xa, fa);

    for (int c = 0; c < 32; ++c) {
        const int d0 = c * 64;
        wg_barrier();  // LDS free (previous compute finished reading)
#pragma unroll
        for (int p = 0; p < 4; ++p) {
            int v = tid + 256 * p;
            int r = v >> 4, dd = (v & 15) << 2;
            *(float4*)&Xs[r][dd] = xa[p];
            *(float4*)&Fs[r][dd] = fa[p];  // for F: r is d-index, dd is q-index (same map)
            // passthrough copy (d_out+1 is only 4B-aligned -> scalar stores)
            float* op = out + 1 + (long long)(n0 + r) * DD + d0 + dd;
            op[0] = xa[p].x; op[1] = xa[p].y; op[2] = xa[p].z; op[3] = xa[p].w;
        }
        if (c + 1 < 32) STAGE_LOAD(d0 + 64, xb, fb);
        wg_barrier();  // LDS ready; prefetch loads remain in flight during compute

#pragma unroll 4
        for (int k4 = 0; k4 < 16; ++k4) {
            float X_[4][4], F_[4][4];
#pragma unroll
            for (int i = 0; i < 4; ++i)
                f4_to_arr(*(const float4*)&Xs[r0 + i][k4 * 4], X_[i]);
#pragma unroll
            for (int j = 0; j < 4; ++j)
                f4_to_arr(*(const float4*)&Fs[k4 * 4 + j][q0], F_[j]);
#pragma unroll
            for (int ri = 0; ri < 4; ++ri)
#pragma unroll
                for (int qi = 0; qi < 4; ++qi) {
                    float s = acc[ri][qi];
#pragma unroll
                    for (int k = 0; k < 4; ++k) s = fmaf(X_[ri][k], F_[k][qi], s);
                    acc[ri][qi] = s;
                }
        }
#pragma unroll
        for (int p = 0; p < 4; ++p) { xa[p] = xb[p]; fa[p] = fb[p]; }
    }

    // masked online reduction, y-domain (y = x / TEMP)
    const float invT = 1.0f / TEMP;
    float m_t[4], s_t[4], p_t[4];
#pragma unroll
    for (int qi = 0; qi < 4; ++qi) { m_t[qi] = -3.4e38f; s_t[qi] = 0.f; p_t[qi] = 3.4e38f; }
#pragma unroll
    for (int ri = 0; ri < 4; ++ri) {
        int lab = lab_s[r0 + ri];
#pragma unroll
        for (int qi = 0; qi < 4; ++qi) {
            float y = acc[ri][qi] * invT;
            if (lab == blab_s[q0 + qi]) {
                p_t[qi] = fminf(p_t[qi], y);
            } else {
                if (y > m_t[qi]) { s_t[qi] = s_t[qi] * __expf(m_t[qi] - y) + 1.0f; m_t[qi] = y; }
                else             { s_t[qi] += __expf(y - m_t[qi]); }
            }
        }
    }
#pragma unroll
    for (int qi = 0; qi < 4; ++qi) {
        red_m[ty][q0 + qi] = m_t[qi];
        red_s[ty][q0 + qi] = s_t[qi];
        red_p[ty][q0 + qi] = p_t[qi];
    }
    __syncthreads();
    if (tid < 64) {
        float M = -3.4e38f, S = 0.f, P = 3.4e38f;
#pragma unroll 4
        for (int t = 0; t < 16; ++t) {
            float m = red_m[t][tid], s = red_s[t][tid], p = red_p[t][tid];
            if (m > M) { S = S * __expf(M - m) + s; M = m; }
            else       { S += s * __expf(m - M); }
            P = fminf(P, p);
        }
        Wm[tid * 256 + blockIdx.x] = M;
        Ws[tid * 256 + blockIdx.x] = S;
        Wp[tid * 256 + blockIdx.x] = P;
    }
}

// K2: combine partials -> loss at d_out[0]
__global__ void k_loss(const float* __restrict__ Wm, const float* __restrict__ Ws,
                       const float* __restrict__ Wp, float* __restrict__ out) {
    const int q = threadIdx.x;  // 64 threads = 1 wave
    float M = -3.4e38f, S = 0.f, P = 3.4e38f;
    for (int i = 0; i < 256; ++i) {
        float m = Wm[q * 256 + i], s = Ws[q * 256 + i], p = Wp[q * 256 + i];
        if (m > M) { S = S * __expf(M - m) + s; M = m; }
        else       { S += s * __expf(m - M); }
        P = fminf(P, p);
    }
    // logits = [P, negatives...] (y-domain); loss_row = LSE - P
    float Mall = fmaxf(M, P);
    float lse  = Mall + logf(S * __expf(M - Mall) + __expf(P - Mall));
    float loss = lse - P;
    for (int off = 32; off > 0; off >>= 1) loss += __shfl_down(loss, off, 64);
    if (q == 0) out[0] = loss * (1.0f / 64.0f);
}

// K3: momentum update of the 64 indexed rows (last-wins on duplicate indexes)
__global__ __launch_bounds__(256) void k_update(const float* __restrict__ feat,
                                                const float* __restrict__ f_weak,
                                                const int* __restrict__ indexes,
                                                float* __restrict__ out) {
    const int b = blockIdx.x;
    const int idx = indexes[b];
    for (int b2 = b + 1; b2 < 64; ++b2)
        if (indexes[b2] == idx) return;  // a later write wins; whole block exits
    const int tid = threadIdx.x;
    float w[8];
    float ss = 0.f;
#pragma unroll
    for (int k = 0; k < 8; ++k) {
        int d = tid + 256 * k;
        float v = feat[(long long)idx * DD + d] * 0.2f + f_weak[b * DD + d] * 0.8f;
        w[k] = v;
        ss += v * v;
    }
    for (int off = 32; off > 0; off >>= 1) ss += __shfl_down(ss, off, 64);
    __shared__ float red[4];
    if ((tid & 63) == 0) red[tid >> 6] = ss;
    __syncthreads();
    float tot = red[0] + red[1] + red[2] + red[3];
    float inv = 1.0f / fmaxf(sqrtf(tot), 1e-12f);
#pragma unroll
    for (int k = 0; k < 8; ++k) {
        int d = tid + 256 * k;
        out[1 + (long long)idx * DD + d] = w[k] * inv;
    }
}

extern "C" void kernel_launch(void* const* d_in, const int* in_sizes, int n_in,
                              void* d_out, int out_size, void* d_ws, size_t ws_size,
                              hipStream_t stream) {
    const float* f       = (const float*)d_in[0];
    const float* f_weak  = (const float*)d_in[1];
    const int*   indexes = (const int*)d_in[2];
    const float* feat    = (const float*)d_in[3];
    const int*   labels  = (const int*)d_in[4];
    float* out = (float*)d_out;
    float* ws  = (float*)d_ws;

    float* fT   = ws;
    int*   blab = (int*)(ws + 131072);
    float* Wm   = ws + 131136;
    float* Wsum = Wm + 64 * 256;
    float* Wp   = Wsum + 64 * 256;

    k_prep<<<32, 256, 0, stream>>>(f, indexes, labels, fT, blab);
    k_main<<<256, 256, 0, stream>>>(feat, fT, labels, blab, out, Wm, Wsum, Wp);
    k_loss<<<1, 64, 0, stream>>>(Wm, Wsum, Wp, out);
    k_update<<<64, 256, 0, stream>>>(feat, f_weak, indexes, out);
}

// Round 2
// 342.009 us; speedup vs baseline: 1.1982x; 1.1982x over previous
//
#include <hip/hip_runtime.h>
#include <math.h>

#define DD   2048
#define TEMP 0.07f
#define GRID_MAIN 1024
#define NROWS 16          // feature rows per block
#define DC    128         // k-chunk per LDS stage
#define NCH   (DD / DC)   // 16 chunks

typedef __attribute__((ext_vector_type(8))) short short8;
typedef __attribute__((ext_vector_type(4))) float f32x4;

// ws layout (float offsets):
//   fA   [65536]  (131072 ushort: f in MFMA A-frag order [w][ksg][lane][j])
//   blab [64]     at 65536 (int)
//   Wm   [1024*64] at 65600
//   Ws   [1024*64] at 131136
//   Wp   [1024*64] at 196672

__device__ __forceinline__ void wg_barrier() {
    // drain LDS ops only (not vmcnt) so global prefetch stays in flight
    asm volatile("s_waitcnt lgkmcnt(0)\ns_barrier" ::: "memory");
}

__device__ __forceinline__ unsigned short to_bf16(float x) {
    union { float f; unsigned u; } v; v.f = x;
    unsigned r = v.u + 0x7fffu + ((v.u >> 16) & 1u);   // RNE
    return (unsigned short)(r >> 16);
}

// K0: f [64][2048] fp32 -> fA bf16 in A-fragment order; gather batch labels.
// A-frag (16x16x32): m = lane&15, k = ksg*32 + (lane>>4)*8 + j
__global__ __launch_bounds__(256) void k_prep(const float* __restrict__ f,
                                              const int* __restrict__ indexes,
                                              const int* __restrict__ labels,
                                              unsigned short* __restrict__ fA,
                                              int* __restrict__ blab) {
    const int q  = blockIdx.x;    // 0..63
    const int kc = threadIdx.x;   // k = kc*8
    const float* src = f + (size_t)q * DD + kc * 8;
    float4 a = *(const float4*)src;
    float4 b = *(const float4*)(src + 4);
    uint4 u;
    u.x = (unsigned)to_bf16(a.x) | ((unsigned)to_bf16(a.y) << 16);
    u.y = (unsigned)to_bf16(a.z) | ((unsigned)to_bf16(a.w) << 16);
    u.z = (unsigned)to_bf16(b.x) | ((unsigned)to_bf16(b.y) << 16);
    u.w = (unsigned)to_bf16(b.z) | ((unsigned)to_bf16(b.w) << 16);
    const int w = q >> 4, ksg = kc >> 2;
    const int lane = (q & 15) | ((kc & 3) << 4);
    *(uint4*)(fA + ((size_t)(w * 64 + ksg) * 64 + lane) * 8) = u;
    if (q == 0 && kc < 64) blab[kc] = labels[indexes[kc]];
}

// K1: per block: 16 feature rows. Streams feat once:
//  (a) aligned passthrough copy to out+1 (shuffle-realigned 16B stores)
//  (b) bf16 convert -> LDS B-frags -> MFMA vs fA  => mat[q][n]
//  (c) masked online (negmax,sumexp,posmin) partials per block
__global__ __launch_bounds__(256) void k_main(const float* __restrict__ feat,
                                              const unsigned short* __restrict__ fA,
                                              const int* __restrict__ labels,
                                              const int* __restrict__ blab,
                                              float* __restrict__ out,
                                              float* __restrict__ Wm,
                                              float* __restrict__ Ws,
                                              float* __restrict__ Wp) {
    __shared__ uint4 Bf[4 * 64];            // [ks][lane] B-fragments, 4 KB
    __shared__ float red_m[16][68], red_s[16][68], red_p[16][68];
    __shared__ int lab_s[16], blab_s[64];

    const int tid = threadIdx.x;
    const int w   = tid >> 6;               // wave id = q-tile
    const int l   = tid & 63;               // lane
    const int n0  = blockIdx.x * NROWS;

    if (tid < 16) lab_s[tid] = labels[n0 + tid];
    if (tid >= 64 && tid < 128) blab_s[tid - 64] = blab[tid - 64];

    const int rh = l >> 5;                  // row half within wave
    const int c  = l & 31;                  // float4 column within 128-k chunk
    const int r0_ = w * 2 + rh;             // pass p covers row p*8 + r0_
    f32x4 acc = {0.f, 0.f, 0.f, 0.f};

    float4 Fa[2], Fb[2];
#pragma unroll
    for (int p = 0; p < 2; ++p)
        Fa[p] = *(const float4*)&feat[(size_t)(n0 + p * 8 + r0_) * DD + 4 * c];

    for (int ch = 0; ch < NCH; ++ch) {
        const int k0 = ch * DC;
        wg_barrier();                       // prior compute done reading Bf
#pragma unroll
        for (int p = 0; p < 2; ++p) {
            const int r = p * 8 + r0_;
            float4 F = Fa[p];
            // shuffle-realign: lane c stores {F.w, next.xyz} at 16B-aligned out
            float nx = __shfl_down(F.x, 1);
            float ny = __shfl_down(F.y, 1);
            float nz = __shfl_down(F.z, 1);
            size_t rowbase = (size_t)(n0 + r) * DD + k0;   // out[j] = feat[j-1]
            if (c < 31) {
                float4 st = make_float4(F.w, nx, ny, nz);
                *(float4*)(out + rowbase + 4 * (c + 1)) = st;
            } else {
                out[rowbase + 128] = F.w;                  // chunk tail
            }
            if (c == 0) {                                  // chunk head (3 floats)
                out[rowbase + 1] = F.x;
                out[rowbase + 2] = F.y;
                out[rowbase + 3] = F.z;
            }
            // bf16 -> LDS B-frag: B[k][n], n=lane&15, k=(lane>>4)*8+j
            unsigned u0 = (unsigned)to_bf16(F.x) | ((unsigned)to_bf16(F.y) << 16);
            unsigned u1 = (unsigned)to_bf16(F.z) | ((unsigned)to_bf16(F.w) << 16);
            int ks    = c >> 3;
            int lanef = (r & 15) | (((c >> 1) & 3) << 4);
            ((uint2*)Bf)[(ks * 64 + lanef) * 2 + (c & 1)] = make_uint2(u0, u1);
        }
        if (ch + 1 < NCH) {                 // prefetch next chunk
#pragma unroll
            for (int p = 0; p < 2; ++p)
                Fb[p] = *(const float4*)&feat[(size_t)(n0 + p * 8 + r0_) * DD + k0 + DC + 4 * c];
        }
        wg_barrier();                       // Bf writes visible; vmcnt NOT drained
#pragma unroll
        for (int ks = 0; ks < 4; ++ks) {
            uint4 araw = *(const uint4*)(fA + ((size_t)(w * 64 + ch * 4 + ks) * 64 + l) * 8);
            uint4 braw = Bf[ks * 64 + l];
            acc = __builtin_amdgcn_mfma_f32_16x16x32_bf16(
                __builtin_bit_cast(short8, araw), __builtin_bit_cast(short8, braw), acc, 0, 0, 0);
        }
        Fa[0] = Fb[0]; Fa[1] = Fb[1];
    }

    // epilogue: C/D layout col(n)=lane&15, row(q in tile)=(lane>>4)*4+reg
    const float invT = 1.0f / TEMP;
    const int nl = l & 15;
    const int g  = l >> 4;
    const int lab = lab_s[nl];
#pragma unroll
    for (int r = 0; r < 4; ++r) {
        int q = w * 16 + g * 4 + r;
        float y = acc[r] * invT;
        bool match = (lab == blab_s[q]);
        red_m[nl][q] = match ? -3.4e38f : y;
        red_s[nl][q] = match ? 0.f : 1.f;
        red_p[nl][q] = match ? y : 3.4e38f;
    }
    __syncthreads();
    if (tid < 64) {
        float M = -3.4e38f, S = 0.f, P = 3.4e38f;
#pragma unroll 4
        for (int i = 0; i < 16; ++i) {
            float m = red_m[i][tid], s = red_s[i][tid], p = red_p[i][tid];
            if (m > M) { S = S * __expf(M - m) + s; M = m; }
            else       { S += s * __expf(m - M); }
            P = fminf(P, p);
        }
        Wm[blockIdx.x * 64 + tid] = M;
        Ws[blockIdx.x * 64 + tid] = S;
        Wp[blockIdx.x * 64 + tid] = P;
    }
}

// K2: combine 1024 partials/query -> loss at out[0]
__global__ __launch_bounds__(256) void k_loss(const float* __restrict__ Wm,
                                              const float* __restrict__ Ws,
                                              const float* __restrict__ Wp,
                                              float* __restrict__ out) {
    __shared__ float Lm[4][64], Ls[4][64], Lp[4][64];
    const int t = threadIdx.x, q = t & 63, ci = t >> 6;
    float M = -3.4e38f, S = 0.f, P = 3.4e38f;
    for (int i = ci * 256; i < ci * 256 + 256; ++i) {
        float m = Wm[i * 64 + q], s = Ws[i * 64 + q], p = Wp[i * 64 + q];
        if (m > M) { S = S * __expf(M - m) + s; M = m; }
        else       { S += s * __expf(m - M); }
        P = fminf(P, p);
    }
    Lm[ci][q] = M; Ls[ci][q] = S; Lp[ci][q] = P;
    __syncthreads();
    if (t < 64) {
        M = -3.4e38f; S = 0.f; P = 3.4e38f;
#pragma unroll
        for (int i = 0; i < 4; ++i) {
            float m = Lm[i][t], s = Ls[i][t], p = Lp[i][t];
            if (m > M) { S = S * __expf(M - m) + s; M = m; }
            else       { S += s * __expf(m - M); }
            P = fminf(P, p);
        }
        float Mall = fmaxf(M, P);
        float lse  = Mall + logf(S * __expf(M - Mall) + __expf(P - Mall));
        float loss = lse - P;
        for (int off = 32; off > 0; off >>= 1) loss += __shfl_down(loss, off, 64);
        if (t == 0) out[0] = loss * (1.0f / 64.0f);
    }
}

// K3: momentum update of the 64 indexed rows (last-wins on duplicates)
__global__ __launch_bounds__(256) void k_update(const float* __restrict__ feat,
                                                const float* __restrict__ f_weak,
                                                const int* __restrict__ indexes,
                                                float* __restrict__ out) {
    const int b = blockIdx.x;
    const int idx = indexes[b];
    for (int b2 = b + 1; b2 < 64; ++b2)
        if (indexes[b2] == idx) return;     // uniform over block
    const int tid = threadIdx.x;
    float wv[8];
    float ss = 0.f;
#pragma unroll
    for (int k = 0; k < 8; ++k) {
        int d = tid + 256 * k;
        float v = feat[(size_t)idx * DD + d] * 0.2f + f_weak[(size_t)b * DD + d] * 0.8f;
        wv[k] = v;
        ss += v * v;
    }
    for (int off = 32; off > 0; off >>= 1) ss += __shfl_down(ss, off, 64);
    __shared__ float red[4];
    if ((tid & 63) == 0) red[tid >> 6] = ss;
    __syncthreads();
    float tot = red[0] + red[1] + red[2] + red[3];
    float inv = 1.0f / fmaxf(sqrtf(tot), 1e-12f);
#pragma unroll
    for (int k = 0; k < 8; ++k) {
        int d = tid + 256 * k;
        out[1 + (size_t)idx * DD + d] = wv[k] * inv;
    }
}

extern "C" void kernel_launch(void* const* d_in, const int* in_sizes, int n_in,
                              void* d_out, int out_size, void* d_ws, size_t ws_size,
                              hipStream_t stream) {
    const float* f       = (const float*)d_in[0];
    const float* f_weak  = (const float*)d_in[1];
    const int*   indexes = (const int*)d_in[2];
    const float* feat    = (const float*)d_in[3];
    const int*   labels  = (const int*)d_in[4];
    float* out = (float*)d_out;
    float* ws  = (float*)d_ws;

    unsigned short* fA = (unsigned short*)ws;          // 131072 ushort
    int*   blab = (int*)(ws + 65536);
    float* Wm   = ws + 65600;
    float* Wsm  = ws + 131136;
    float* Wp   = ws + 196672;

    k_prep<<<64, 256, 0, stream>>>(f, indexes, labels, fA, blab);
    k_main<<<GRID_MAIN, 256, 0, stream>>>(feat, fA, labels, blab, out, Wm, Wsm, Wp);
    k_loss<<<1, 256, 0, stream>>>(Wm, Wsm, Wp, out);
    k_update<<<64, 256, 0, stream>>>(feat, f_weak, indexes, out);
}